// Round 3
// baseline (363.117 us; speedup 1.0000x reference)
//
#include <hip/hip_runtime.h>
#include <math.h>

// Problem constants
// B=4, H=W=64 -> L=4096, DIM=128, D_INNER=256, D_STATE=16, D_CONV=4, DT_RANK=8, NSLICES=16
#define LSEQ 4096

// Workspace layout (floats). Total ~140 MB (proven to fit)
#define XZ_OFF   0ULL
#define XZ_SZ    (4ULL * 4096 * 512)
#define U_OFF    (XZ_OFF + XZ_SZ)
#define DIR_SZ   (4ULL * 256 * 4096)        // per direction
#define DELTA_OFF (U_OFF + 3ULL * DIR_SZ)   // delta; also holds wT_in before front runs
#define BC_OFF   (DELTA_OFF + 3ULL * DIR_SZ)
#define BC_SZ    (4ULL * 4096 * 32)         // per dir: B blocked [b][1024][16][4] then C blocked
#define WTIN_OFF DELTA_OFF                  // wT_in[128][512]; delta written later by front
#define WTOUT_OFF U_OFF                     // wT_out[256][128]; u dead after scan

typedef float v2f __attribute__((ext_vector_type(2)));
typedef float v4f __attribute__((ext_vector_type(4)));

__device__ __forceinline__ float sigmoidf_(float x) { return 1.0f / (1.0f + __expf(-x)); }
__device__ __forceinline__ float siluf_(float x)    { return x * sigmoidf_(x); }

// 2^x via HW transcendental.
__device__ __forceinline__ float fast_exp2_asm(float x) {
    float r;
    asm volatile("v_exp_f32 %0, %1\n\ts_nop 0" : "=v"(r) : "v"(x));
    return r;
}
#if defined(__has_builtin)
#if __has_builtin(__builtin_amdgcn_exp2f)
#define EXP2(x) __builtin_amdgcn_exp2f(x)
#else
#define EXP2(x) fast_exp2_asm(x)
#endif
#else
#define EXP2(x) fast_exp2_asm(x)
#endif

// softplus via HW exp2/log2: ln(1+e^x) = ln2 * log2(1 + 2^(x*log2e))
__device__ __forceinline__ float softplus_fast(float x) {
    float t = EXP2(1.44269504f * x);
    float r = 0.69314718f * __log2f(1.0f + t);
    return (x > 20.0f) ? x : r;
}

// dir permutation: scan-domain index j -> original-domain index
__device__ __forceinline__ int perm_idx(int dir, int j) {
    if (dir == 0) return j;
    if (dir == 1) return 4095 - j;
    return ((j & 15) << 8) | (j >> 4);   // slice: j = jj*16+s -> s*256+jj
}

// DPP cross-lane move (VALU pipe, no LDS). ctrl must be a literal.
// 0xB1 = quad pair-swap, 0x4E = quad half-swap, 0x124 = row_ror:4, 0x128 = row_ror:8
#define DPP_MOV(x, ctrl) __int_as_float(__builtin_amdgcn_update_dpp(0, __float_as_int(x), (ctrl), 0xF, 0xF, true))

// ---------------------------------------------------------------------------
// K0: wT_in[c][p] = in_proj_w[p][c]   (128 x 512)
__global__ __launch_bounds__(256) void transpose_in_kernel(const float* __restrict__ w,
                                                           float* __restrict__ wT) {
    int idx = blockIdx.x * 256 + threadIdx.x;   // 65536
    int p = idx >> 7, c = idx & 127;
    wT[(size_t)c * 512 + p] = w[(size_t)p * 128 + c];
}

// ---------------------------------------------------------------------------
// K1: xz[b][l][p] = sum_c wT_in[c][p] * x_in[b][l][c]
__global__ __launch_bounds__(256) void inproj_kernel(const float* __restrict__ x,
                              const float* __restrict__ wT,
                              float* __restrict__ xz) {
    const int b = blockIdx.y;
    const int l0 = blockIdx.x * 16;
    __shared__ float xs[128 * 20];   // [c][l]
    for (int idx = threadIdx.x; idx < 16 * 128; idx += 256) {
        int li = idx >> 7, c = idx & 127;
        xs[c * 20 + li] = x[((size_t)(b * 4096 + l0 + li)) * 128 + c];
    }
    __syncthreads();
    const int p0 = (threadIdx.x & 127) * 4;
    const int g8 = (threadIdx.x >> 7) * 8;
    float acc[4][8];
    #pragma unroll
    for (int j = 0; j < 4; ++j)
        #pragma unroll
        for (int k = 0; k < 8; ++k) acc[j][k] = 0.0f;
    for (int c = 0; c < 128; ++c) {
        float4 wv = *(const float4*)(wT + (size_t)c * 512 + p0);
        const float* xp = xs + c * 20 + g8;
        float4 x0 = *(const float4*)(xp);
        float4 x1 = *(const float4*)(xp + 4);
        float xv[8] = {x0.x, x0.y, x0.z, x0.w, x1.x, x1.y, x1.z, x1.w};
        float wj[4] = {wv.x, wv.y, wv.z, wv.w};
        #pragma unroll
        for (int j = 0; j < 4; ++j)
            #pragma unroll
            for (int k = 0; k < 8; ++k) acc[j][k] += wj[j] * xv[k];
    }
    #pragma unroll
    for (int k = 0; k < 8; ++k) {
        float4 s; s.x = acc[0][k]; s.y = acc[1][k]; s.z = acc[2][k]; s.w = acc[3][k];
        *(float4*)(xz + ((size_t)(b * 4096 + l0 + g8 + k)) * 512 + p0) = s;
    }
}

// ---------------------------------------------------------------------------
// K2 (fused conv+silu+x_proj+dt, ALL dirs): per (32-scan-l tile, b, dir).
__global__ __launch_bounds__(256) void front_kernel(float* __restrict__ ws,
        const float* __restrict__ xw0, const float* __restrict__ xw1, const float* __restrict__ xw2,
        const float* __restrict__ dw0, const float* __restrict__ dw1, const float* __restrict__ dw2,
        const float* __restrict__ db0, const float* __restrict__ db1, const float* __restrict__ db2,
        const float* __restrict__ cw0, const float* __restrict__ cb0,
        const float* __restrict__ cw1, const float* __restrict__ cb1,
        const float* __restrict__ cw2, const float* __restrict__ cb2) {
    const int l0 = blockIdx.x * 32, b = blockIdx.y, dir = blockIdx.z;
    const float* xw = (dir == 0) ? xw0 : (dir == 1) ? xw1 : xw2;
    const float* dw = (dir == 0) ? dw0 : (dir == 1) ? dw1 : dw2;
    const float* db = (dir == 0) ? db0 : (dir == 1) ? db1 : db2;
    const float* cw = (dir == 0) ? cw0 : (dir == 1) ? cw1 : cw2;
    const float* cb = (dir == 0) ? cb0 : (dir == 1) ? cb1 : cb2;
    const float* xzb = ws + XZ_OFF + (size_t)b * 4096 * 512;
    float* ub      = ws + U_OFF + (size_t)dir * DIR_SZ + (size_t)b * 256 * 4096;
    float* deltab  = ws + DELTA_OFF + (size_t)dir * DIR_SZ + (size_t)b * 256 * 4096;
    float* Bf      = ws + BC_OFF + (size_t)dir * BC_SZ;
    float* Cf      = Bf + BC_SZ / 2;

    __shared__ float xt[35 * 260];   // staging [k][d]
    __shared__ float xd[40 * 33];
    __shared__ float xws[40 * 68];   // xw 64-col tile, stride 68 spreads banks across rows
    float* ut = xt;                  // reused after conv: [li][264] swizzled

    // ---- stage 35 rows, each a coalesced 1KB read of xz[row][0..255]
    for (int idx = threadIdx.x; idx < 35 * 64; idx += 256) {
        int k = idx >> 6, dq = idx & 63;
        int j = l0 - 3 + k;
        float4 v = {0.f, 0.f, 0.f, 0.f};
        if (j >= 0) {
            int row = (dir == 0) ? j : (dir == 1) ? (4095 - j) : (((j & 15) << 8) | (j >> 4));
            v = *(const float4*)(xzb + (size_t)row * 512 + dq * 4);
        }
        *(float4*)(xt + k * 260 + dq * 4) = v;
    }
    __syncthreads();

    // ---- conv + silu, thread = d row
    const int d = threadIdx.x;
    const float w0 = cw[d * 4 + 0], w1 = cw[d * 4 + 1], w2 = cw[d * 4 + 2], w3 = cw[d * 4 + 3];
    const float bb = cb[d];
    float win[35];
    #pragma unroll
    for (int k = 0; k < 35; ++k) win[k] = xt[k * 260 + d];
    float r[32];
    #pragma unroll
    for (int li = 0; li < 32; ++li)
        r[li] = siluf_(bb + w0 * win[li] + w1 * win[li + 1] + w2 * win[li + 2] + w3 * win[li + 3]);
    {
        float* urow = ub + (size_t)d * 4096 + l0;
        #pragma unroll
        for (int q = 0; q < 8; ++q) {
            float4 v; v.x = r[q*4]; v.y = r[q*4+1]; v.z = r[q*4+2]; v.w = r[q*4+3];
            *(float4*)(urow + q * 4) = v;
        }
    }
    __syncthreads();   // all xt reads done before ut overwrite

    #pragma unroll
    for (int li = 0; li < 32; ++li)
        ut[li * 264 + 4 * (((d >> 2) ^ (li & 7))) + (d & 3)] = r[li];

    // ---- 40x256 GEMM: xd[40][32] = xw @ u-tile, xw LDS-staged in 64-col tiles
    {
        const int rg = threadIdx.x >> 5;
        const int li = threadIdx.x & 31;
        float acc[5];
        #pragma unroll
        for (int j = 0; j < 5; ++j) acc[j] = 0.0f;
        const float* up = ut + li * 264;
        const int sw = (li & 7);
        for (int ct = 0; ct < 4; ++ct) {
            __syncthreads();        // ut ready (ct=0) / previous tile's reads done
            for (int idx = threadIdx.x; idx < 40 * 16; idx += 256) {
                int rr = idx >> 4, q = (idx & 15) * 4;
                *(float4*)(xws + rr * 68 + q) = *(const float4*)(xw + (size_t)rr * 256 + ct * 64 + q);
            }
            __syncthreads();
            #pragma unroll 4
            for (int c4t = 0; c4t < 16; ++c4t) {
                const int cc = 4 * (c4t ^ sw);           // tile-local column
                float4 uv = *(const float4*)(up + ct * 64 + cc);
                #pragma unroll
                for (int j = 0; j < 5; ++j) {
                    float4 wv = *(const float4*)(xws + (rg * 5 + j) * 68 + cc);
                    acc[j] += wv.x * uv.x + wv.y * uv.y + wv.z * uv.z + wv.w * uv.w;
                }
            }
        }
        #pragma unroll
        for (int j = 0; j < 5; ++j) xd[(rg * 5 + j) * 33 + li] = acc[j];
    }
    __syncthreads();

    // ---- B/C blocked writes (wave-coalesced) + delta
    {
        const int wv = threadIdx.x >> 6;
        const int lane = threadIdx.x & 63;
        const int n = lane >> 2, lq = lane & 3;
        #pragma unroll
        for (int j = 0; j < 2; ++j) {
            int l4 = (l0 >> 2) + j * 4 + wv;
            int li = (j * 4 + wv) * 4 + lq;
            size_t base = (((size_t)b * 1024 + l4) * 16 + n) * 4 + lq;
            Bf[base] = xd[(8 + n) * 33 + li];
            Cf[base] = xd[(24 + n) * 33 + li];
        }
    }
    {
        const int li = threadIdx.x & 31;
        float xr8[8];
        #pragma unroll
        for (int rr = 0; rr < 8; ++rr) xr8[rr] = xd[rr * 33 + li];
        #pragma unroll
        for (int k = 0; k < 32; ++k) {
            int dd = ((threadIdx.x + k * 256) >> 5);
            float4 wa = *(const float4*)(dw + dd * 8);
            float4 wb = *(const float4*)(dw + dd * 8 + 4);
            float acc = db[dd]
                + wa.x * xr8[0] + wa.y * xr8[1] + wa.z * xr8[2] + wa.w * xr8[3]
                + wb.x * xr8[4] + wb.y * xr8[5] + wb.z * xr8[6] + wb.w * xr8[7];
            deltab[(size_t)dd * 4096 + l0 + li] = softplus_fast(acc);
        }
    }
}

// ---------------------------------------------------------------------------
// K3: chunked selective scan. Block = 2 d-rows of one (b,dir): 1024 thr =
// 32 chunks x 2 d x 16 states, lane = c*32 + d2*16 + n. B/C addresses are
// d-independent, so the d2=0/d2=1 lane halves issue duplicate addresses that
// the TA coalesces -> B/C L2 traffic halves vs 1 d/block.
// Pass-2 y-reduce: shared DPP butterfly (elements merged into lanes after 2
// private levels; last 2 levels + selects shared) = 23 wave-insts per 8 outputs.
__global__ __launch_bounds__(1024, 8) void scan_kernel(float* __restrict__ ws,
                            const float* __restrict__ Al0, const float* __restrict__ Dp0,
                            const float* __restrict__ Al1, const float* __restrict__ Dp1,
                            const float* __restrict__ Al2, const float* __restrict__ Dp2) {
    const int d0 = blockIdx.x * 2, b = blockIdx.y, dir = blockIdx.z;
    const float* Al = (dir == 0) ? Al0 : (dir == 1) ? Al1 : Al2;
    const float* Dp = (dir == 0) ? Dp0 : (dir == 1) ? Dp1 : Dp2;
    const int n  = threadIdx.x & 15;        // state 0..15
    const int d2 = (threadIdx.x >> 4) & 1;  // which d row
    const int c  = threadIdx.x >> 5;        // chunk 0..31
    const int nl = n & 7;
    const int d = d0 + d2;
    const float Ane = -1.44269504f * __expf(Al[d * 16 + n]);
    const v2f AneD = {Ane, Ane};
    const float Dd = Dp[d];
    const float* ubase = ws + U_OFF + (size_t)dir * DIR_SZ + ((size_t)(b * 256 + d0)) * 4096;
    float* dbase = ws + DELTA_OFF + (size_t)dir * DIR_SZ + ((size_t)(b * 256 + d0)) * 4096;
    const float* urow = ubase + (size_t)d2 * 4096;
    float* drow = dbase + (size_t)d2 * 4096;

    __shared__ float sdu[2][32 * 260];
    __shared__ float ps[2][1024];          // per d: P[32][16] then S[32][16]

    // stage both d rows: (delta quad | u quad) interleaved per 4 l
    for (int i = threadIdx.x; i < 2048; i += 1024) {
        int dsl = i >> 10, ii = i & 1023;
        float4 dv = ((const float4*)(dbase + (size_t)dsl * 4096))[ii];
        float4 uv = ((const float4*)(ubase + (size_t)dsl * 4096))[ii];
        int l = ii * 4;
        float* p = sdu[dsl] + (l >> 7) * 260 + (l & 127) * 2;
        *(float4*)(p) = dv; *(float4*)(p + 4) = uv;
    }
    __syncthreads();

    const v4f* Bq = (const v4f*)(ws + BC_OFF + (size_t)dir * BC_SZ)
                       + ((size_t)b * 1024 + c * 32) * 16 + n;
    const v4f* Cq = (const v4f*)(ws + BC_OFF + (size_t)dir * BC_SZ + BC_SZ / 2)
                       + ((size_t)b * 1024 + c * 32) * 16 + n;
    const v4f* sp = (const v4f*)(sdu[d2] + c * 260);
    float* Psh = ps[d2];
    float* Ssh = ps[d2] + 512;

    // Pass 1: local scan + decay-sum (packed mul pairs, fma chain)
    float S = 0.0f;
    v2f ds2 = {0.0f, 0.0f};
    #pragma unroll 8
    for (int k4 = 0; k4 < 32; ++k4) {
        v4f dq = sp[k4 * 2], uq = sp[k4 * 2 + 1];
        v4f Bv = Bq[(size_t)k4 * 16];
        v2f du0 = dq.xy * uq.xy;
        v2f du1 = dq.zw * uq.zw;
        v2f t0 = AneD * dq.xy;
        v2f t1 = AneD * dq.zw;
        v2f p0 = du0 * Bv.xy;
        v2f p1 = du1 * Bv.zw;
        ds2 += dq.xy + dq.zw;
        S = __builtin_fmaf(S, EXP2(t0.x), p0.x);
        S = __builtin_fmaf(S, EXP2(t0.y), p0.y);
        S = __builtin_fmaf(S, EXP2(t1.x), p1.x);
        S = __builtin_fmaf(S, EXP2(t1.y), p1.y);
    }
    Ssh[c * 16 + n] = S;
    Psh[c * 16 + n] = EXP2(Ane * (ds2.x + ds2.y));
    __syncthreads();
    float h = 0.0f;
    #pragma unroll 2
    for (int k = 0; k < c; ++k) h = __builtin_fmaf(h, Psh[k * 16 + n], Ssh[k * 16 + n]);

    // Pass 2: shared DPP butterfly. After 2 private levels each lane holds its
    // quad-sum; merge 4 elements into lanes by (n&1),(n&2); share ror4/ror8.
    for (int g = 0; g < 16; ++g) {
        const int j0 = g * 8 + nl;
        float uo = sdu[d2][c * 260 + ((j0 >> 2) << 3) + 4 + (j0 & 3)];   // u for output
        v4f dq0 = sp[g * 4 + 0], uq0 = sp[g * 4 + 1];
        v4f dq1 = sp[g * 4 + 2], uq1 = sp[g * 4 + 3];
        v4f Bv0 = Bq[(size_t)(g * 2) * 16], Bv1 = Bq[(size_t)(g * 2 + 1) * 16];
        v4f Cv0 = Cq[(size_t)(g * 2) * 16], Cv1 = Cq[(size_t)(g * 2 + 1) * 16];
        v2f t0 = AneD * dq0.xy, t1 = AneD * dq0.zw;
        v2f t2 = AneD * dq1.xy, t3 = AneD * dq1.zw;
        v2f q0 = dq0.xy * uq0.xy, q1 = dq0.zw * uq0.zw;
        v2f q2 = dq1.xy * uq1.xy, q3 = dq1.zw * uq1.zw;
        v2f p0 = q0 * Bv0.xy, p1 = q1 * Bv0.zw;
        v2f p2 = q2 * Bv1.xy, p3 = q3 * Bv1.zw;
        float e0 = EXP2(t0.x), e1 = EXP2(t0.y);
        float e2 = EXP2(t1.x), e3 = EXP2(t1.y);
        float e4 = EXP2(t2.x), e5 = EXP2(t2.y);
        float e6 = EXP2(t3.x), e7 = EXP2(t3.y);
        float ya0, ya1, ya2, ya3, ya4, ya5, ya6, ya7;
        h = __builtin_fmaf(h, e0, p0.x); ya0 = h * Cv0.x;
        h = __builtin_fmaf(h, e1, p0.y); ya1 = h * Cv0.y;
        h = __builtin_fmaf(h, e2, p1.x); ya2 = h * Cv0.z;
        h = __builtin_fmaf(h, e3, p1.y); ya3 = h * Cv0.w;
        h = __builtin_fmaf(h, e4, p2.x); ya4 = h * Cv1.x;
        h = __builtin_fmaf(h, e5, p2.y); ya5 = h * Cv1.y;
        h = __builtin_fmaf(h, e6, p3.x); ya6 = h * Cv1.z;
        h = __builtin_fmaf(h, e7, p3.y); ya7 = h * Cv1.w;
        // level 1: pair sums (private)
        ya0 += DPP_MOV(ya0, 0xB1); ya1 += DPP_MOV(ya1, 0xB1);
        ya2 += DPP_MOV(ya2, 0xB1); ya3 += DPP_MOV(ya3, 0xB1);
        ya4 += DPP_MOV(ya4, 0xB1); ya5 += DPP_MOV(ya5, 0xB1);
        ya6 += DPP_MOV(ya6, 0xB1); ya7 += DPP_MOV(ya7, 0xB1);
        // merge pairs of elements by n&1
        float z0 = (n & 1) ? ya1 : ya0;
        float z1 = (n & 1) ? ya3 : ya2;
        float z2 = (n & 1) ? ya5 : ya4;
        float z3 = (n & 1) ? ya7 : ya6;
        // level 2: quad sums (2 elements per reg)
        z0 += DPP_MOV(z0, 0x4E); z1 += DPP_MOV(z1, 0x4E);
        z2 += DPP_MOV(z2, 0x4E); z3 += DPP_MOV(z3, 0x4E);
        // merge by n&2 -> 4 elements per reg (element index = n&3)
        float w0 = (n & 2) ? z1 : z0;
        float w1 = (n & 2) ? z3 : z2;
        // shared levels 3,4 (ror preserves n&3)
        w0 += DPP_MOV(w0, 0x124); w1 += DPP_MOV(w1, 0x124);
        w0 += DPP_MOV(w0, 0x128); w1 += DPP_MOV(w1, 0x128);
        float ysel = (n & 4) ? w1 : w0;   // lane n holds element (n&4)*... = g*8 + nl
        if (n < 8) drow[perm_idx(dir, c * 128 + j0)] = ysel + Dd * uo;
    }
}

// ---------------------------------------------------------------------------
// K3b: wT_out[d][o] = out_proj_w[o][d]  (runs AFTER scan; lives in dead U region)
__global__ __launch_bounds__(256) void transpose_w_kernel(const float* __restrict__ ow,
                                                          float* __restrict__ wT) {
    int idx = blockIdx.x * 256 + threadIdx.x;   // 32768
    int o = idx >> 8, d = idx & 255;            // read side coalesced (d consecutive)
    wT[(size_t)d * 128 + o] = ow[(size_t)o * 256 + d];
}

// ---------------------------------------------------------------------------
// K4: y_total = silu(z)*(yf+yb+ys); out = wT^T @ y_total.
// wT LDS-staged in 64-row tiles: cuts ~1 GB of redundant L2 reads to 128 MB.
__global__ __launch_bounds__(256) void epilogue_kernel(const float* __restrict__ ws,
                                const float* __restrict__ wT,
                                float* __restrict__ out) {
    const int l0 = blockIdx.x * 16, b = blockIdx.y;
    __shared__ float yt[256 * 20];
    __shared__ float wts[64 * 128];
    const float* yf = ws + DELTA_OFF;
    const float* yb = ws + DELTA_OFF + DIR_SZ;
    const float* ysd = ws + DELTA_OFF + 2 * DIR_SZ;
    const float* xzb = ws + XZ_OFF + (size_t)b * 4096 * 512;

    // phase 1: y-sum, vectorized f4 (coalesced)
    for (int idx = threadIdx.x; idx < 256 * 4; idx += 256) {
        int d = idx >> 2, q = (idx & 3) * 4;
        size_t ro = ((size_t)(b * 256 + d)) * 4096 + l0 + q;
        float4 vf = *(const float4*)(yf + ro);
        float4 vb = *(const float4*)(yb + ro);
        float4 vs = *(const float4*)(ysd + ro);
        float4 s; s.x = vf.x + vb.x + vs.x; s.y = vf.y + vb.y + vs.y;
        s.z = vf.z + vb.z + vs.z; s.w = vf.w + vb.w + vs.w;
        *(float4*)(yt + d * 20 + q) = s;
    }
    __syncthreads();
    // phase 2: multiply silu(z), z read coalesced from xz[b][l][256+d]
    {
        const int d = threadIdx.x;
        #pragma unroll 4
        for (int li = 0; li < 16; ++li) {
            float z = xzb[(size_t)(l0 + li) * 512 + 256 + d];
            yt[d * 20 + li] *= siluf_(z);
        }
    }

    // GEMM: thread = (4 o, 2 l); wT tiled through LDS
    const int o0 = (threadIdx.x & 31) * 4;
    const int lp = (threadIdx.x >> 5) * 2;
    float a0[4], a1[4];
    #pragma unroll
    for (int j = 0; j < 4; ++j) { a0[j] = 0.0f; a1[j] = 0.0f; }
    for (int dt = 0; dt < 4; ++dt) {
        __syncthreads();        // yt ready (dt=0) / previous tile reads done
        for (int idx = threadIdx.x; idx < 64 * 32; idx += 256) {
            int dd = idx >> 5, q = (idx & 31) * 4;
            *(float4*)(wts + dd * 128 + q) = *(const float4*)(wT + (size_t)(dt * 64 + dd) * 128 + q);
        }
        __syncthreads();
        #pragma unroll 4
        for (int dl = 0; dl < 64; ++dl) {
            float4 w = *(const float4*)(wts + dl * 128 + o0);
            float2 y = *(const float2*)(yt + (dt * 64 + dl) * 20 + lp);
            a0[0] += w.x * y.x; a0[1] += w.y * y.x; a0[2] += w.z * y.x; a0[3] += w.w * y.x;
            a1[0] += w.x * y.y; a1[1] += w.y * y.y; a1[2] += w.z * y.y; a1[3] += w.w * y.y;
        }
    }
    float4 s0; s0.x = a0[0]; s0.y = a0[1]; s0.z = a0[2]; s0.w = a0[3];
    float4 s1; s1.x = a1[0]; s1.y = a1[1]; s1.z = a1[2]; s1.w = a1[3];
    *(float4*)(out + ((size_t)(b * 4096 + l0 + lp)) * 128 + o0) = s0;
    *(float4*)(out + ((size_t)(b * 4096 + l0 + lp + 1)) * 128 + o0) = s1;
}

// ---------------------------------------------------------------------------
extern "C" void kernel_launch(void* const* d_in, const int* in_sizes, int n_in,
                              void* d_out, int out_size, void* d_ws, size_t ws_size,
                              hipStream_t stream) {
    const float* x_in = (const float*)d_in[0];
    const float* ipw  = (const float*)d_in[1];
    const float* cw[3]  = {(const float*)d_in[2],  (const float*)d_in[9],  (const float*)d_in[16]};
    const float* cb[3]  = {(const float*)d_in[3],  (const float*)d_in[10], (const float*)d_in[17]};
    const float* xpw[3] = {(const float*)d_in[4],  (const float*)d_in[11], (const float*)d_in[18]};
    const float* dtw[3] = {(const float*)d_in[5],  (const float*)d_in[12], (const float*)d_in[19]};
    const float* dtb[3] = {(const float*)d_in[6],  (const float*)d_in[13], (const float*)d_in[20]};
    const float* alog[3]= {(const float*)d_in[7],  (const float*)d_in[14], (const float*)d_in[21]};
    const float* dp[3]  = {(const float*)d_in[8],  (const float*)d_in[15], (const float*)d_in[22]};
    const float* ow   = (const float*)d_in[23];
    float* ws  = (float*)d_ws;
    float* out = (float*)d_out;

    transpose_in_kernel<<<dim3(256), 256, 0, stream>>>(ipw, ws + WTIN_OFF);
    inproj_kernel<<<dim3(256, 4), 256, 0, stream>>>(x_in, ws + WTIN_OFF, ws);
    front_kernel<<<dim3(128, 4, 3), 256, 0, stream>>>(ws,
        xpw[0], xpw[1], xpw[2], dtw[0], dtw[1], dtw[2], dtb[0], dtb[1], dtb[2],
        cw[0], cb[0], cw[1], cb[1], cw[2], cb[2]);
    scan_kernel<<<dim3(128, 4, 3), 1024, 0, stream>>>(ws,
        alog[0], dp[0], alog[1], dp[1], alog[2], dp[2]);
    transpose_w_kernel<<<dim3(128), 256, 0, stream>>>(ow, ws + WTOUT_OFF);
    epilogue_kernel<<<dim3(256, 4), 256, 0, stream>>>(ws, ws + WTOUT_OFF, out);
}

// Round 4
// 348.817 us; speedup vs baseline: 1.0410x; 1.0410x over previous
//
#include <hip/hip_runtime.h>
#include <math.h>

// Problem constants
// B=4, H=W=64 -> L=4096, DIM=128, D_INNER=256, D_STATE=16, D_CONV=4, DT_RANK=8, NSLICES=16
#define LSEQ 4096

// Workspace layout (floats). Total ~140 MB (proven to fit)
#define XZ_OFF   0ULL
#define XZ_SZ    (4ULL * 4096 * 512)
#define U_OFF    (XZ_OFF + XZ_SZ)
#define DIR_SZ   (4ULL * 256 * 4096)        // per direction
#define DELTA_OFF (U_OFF + 3ULL * DIR_SZ)   // delta; also holds wT_in before front runs
#define BC_OFF   (DELTA_OFF + 3ULL * DIR_SZ)
#define BC_SZ    (4ULL * 4096 * 32)         // per dir: B blocked [b][1024][16][4] then C blocked
#define WTIN_OFF DELTA_OFF                  // wT_in[128][512]; delta written later by front
#define WTOUT_OFF U_OFF                     // wT_out[256][128]; u dead after scan

typedef float v2f __attribute__((ext_vector_type(2)));
typedef float v4f __attribute__((ext_vector_type(4)));

__device__ __forceinline__ float sigmoidf_(float x) { return 1.0f / (1.0f + __expf(-x)); }
__device__ __forceinline__ float siluf_(float x)    { return x * sigmoidf_(x); }

// 2^x via HW transcendental.
__device__ __forceinline__ float fast_exp2_asm(float x) {
    float r;
    asm volatile("v_exp_f32 %0, %1\n\ts_nop 0" : "=v"(r) : "v"(x));
    return r;
}
#if defined(__has_builtin)
#if __has_builtin(__builtin_amdgcn_exp2f)
#define EXP2(x) __builtin_amdgcn_exp2f(x)
#else
#define EXP2(x) fast_exp2_asm(x)
#endif
#else
#define EXP2(x) fast_exp2_asm(x)
#endif

// softplus via HW exp2/log2: ln(1+e^x) = ln2 * log2(1 + 2^(x*log2e))
__device__ __forceinline__ float softplus_fast(float x) {
    float t = EXP2(1.44269504f * x);
    float r = 0.69314718f * __log2f(1.0f + t);
    return (x > 20.0f) ? x : r;
}

// dir permutation: scan-domain index j -> original-domain index
__device__ __forceinline__ int perm_idx(int dir, int j) {
    if (dir == 0) return j;
    if (dir == 1) return 4095 - j;
    return ((j & 15) << 8) | (j >> 4);   // slice: j = jj*16+s -> s*256+jj
}

// DPP cross-lane move (VALU pipe, no LDS). ctrl must be a literal.
// 0xB1 = quad pair-swap, 0x4E = quad half-swap, 0x124 = row_ror:4, 0x128 = row_ror:8
#define DPP_MOV(x, ctrl) __int_as_float(__builtin_amdgcn_update_dpp(0, __float_as_int(x), (ctrl), 0xF, 0xF, true))

// ---------------------------------------------------------------------------
// K0: wT_in[c][p] = in_proj_w[p][c]   (128 x 512)
__global__ __launch_bounds__(256) void transpose_in_kernel(const float* __restrict__ w,
                                                           float* __restrict__ wT) {
    int idx = blockIdx.x * 256 + threadIdx.x;   // 65536
    int p = idx >> 7, c = idx & 127;
    wT[(size_t)c * 512 + p] = w[(size_t)p * 128 + c];
}

// ---------------------------------------------------------------------------
// K1: xz[b][l][p] = sum_c wT_in[c][p] * x_in[b][l][c]
__global__ __launch_bounds__(256) void inproj_kernel(const float* __restrict__ x,
                              const float* __restrict__ wT,
                              float* __restrict__ xz) {
    const int b = blockIdx.y;
    const int l0 = blockIdx.x * 16;
    __shared__ float xs[128 * 20];   // [c][l]
    for (int idx = threadIdx.x; idx < 16 * 128; idx += 256) {
        int li = idx >> 7, c = idx & 127;
        xs[c * 20 + li] = x[((size_t)(b * 4096 + l0 + li)) * 128 + c];
    }
    __syncthreads();
    const int p0 = (threadIdx.x & 127) * 4;
    const int g8 = (threadIdx.x >> 7) * 8;
    float acc[4][8];
    #pragma unroll
    for (int j = 0; j < 4; ++j)
        #pragma unroll
        for (int k = 0; k < 8; ++k) acc[j][k] = 0.0f;
    for (int c = 0; c < 128; ++c) {
        float4 wv = *(const float4*)(wT + (size_t)c * 512 + p0);
        const float* xp = xs + c * 20 + g8;
        float4 x0 = *(const float4*)(xp);
        float4 x1 = *(const float4*)(xp + 4);
        float xv[8] = {x0.x, x0.y, x0.z, x0.w, x1.x, x1.y, x1.z, x1.w};
        float wj[4] = {wv.x, wv.y, wv.z, wv.w};
        #pragma unroll
        for (int j = 0; j < 4; ++j)
            #pragma unroll
            for (int k = 0; k < 8; ++k) acc[j][k] += wj[j] * xv[k];
    }
    #pragma unroll
    for (int k = 0; k < 8; ++k) {
        float4 s; s.x = acc[0][k]; s.y = acc[1][k]; s.z = acc[2][k]; s.w = acc[3][k];
        *(float4*)(xz + ((size_t)(b * 4096 + l0 + g8 + k)) * 512 + p0) = s;
    }
}

// ---------------------------------------------------------------------------
// K2 (fused conv+silu+x_proj+dt, ALL dirs): per (32-scan-l tile, b, dir).
// LDS = 38.5 KB -> 4 blocks/CU (was 52.6 KB -> 3). History rows via direct
// global reads + sliding-window conv; ut XOR-swizzled at stride 256; xd
// aliased into dead ut region; xw staged in 32-col tiles.
__global__ __launch_bounds__(256, 4) void front_kernel(float* __restrict__ ws,
        const float* __restrict__ xw0, const float* __restrict__ xw1, const float* __restrict__ xw2,
        const float* __restrict__ dw0, const float* __restrict__ dw1, const float* __restrict__ dw2,
        const float* __restrict__ db0, const float* __restrict__ db1, const float* __restrict__ db2,
        const float* __restrict__ cw0, const float* __restrict__ cb0,
        const float* __restrict__ cw1, const float* __restrict__ cb1,
        const float* __restrict__ cw2, const float* __restrict__ cb2) {
    const int l0 = blockIdx.x * 32, b = blockIdx.y, dir = blockIdx.z;
    const float* xw = (dir == 0) ? xw0 : (dir == 1) ? xw1 : xw2;
    const float* dw = (dir == 0) ? dw0 : (dir == 1) ? dw1 : dw2;
    const float* db = (dir == 0) ? db0 : (dir == 1) ? db1 : db2;
    const float* cw = (dir == 0) ? cw0 : (dir == 1) ? cw1 : cw2;
    const float* cb = (dir == 0) ? cb0 : (dir == 1) ? cb1 : cb2;
    const float* xzb = ws + XZ_OFF + (size_t)b * 4096 * 512;
    float* ub      = ws + U_OFF + (size_t)dir * DIR_SZ + (size_t)b * 256 * 4096;
    float* deltab  = ws + DELTA_OFF + (size_t)dir * DIR_SZ + (size_t)b * 256 * 4096;
    float* Bf      = ws + BC_OFF + (size_t)dir * BC_SZ;
    float* Cf      = Bf + BC_SZ / 2;

    __shared__ float xt[32 * 256];   // stage rows j=l0..l0+31 [k][d]; reused as swizzled ut; tail as xd
    __shared__ float xws[40 * 36];   // xw 32-col tile (stride 36: rows shift 4 banks)
    float* ut = xt;
    float* xd = xt;                  // [40][33] alias, barrier-separated from ut reads

    // ---- stage 32 rows, each a coalesced 1KB read of xz[row][0..255]
    for (int idx = threadIdx.x; idx < 32 * 64; idx += 256) {
        int k = idx >> 6, dq = idx & 63;
        int j = l0 + k;
        int row = (dir == 0) ? j : (dir == 1) ? (4095 - j) : (((j & 15) << 8) | (j >> 4));
        float4 v = *(const float4*)(xzb + (size_t)row * 512 + dq * 4);
        *(float4*)(xt + k * 256 + dq * 4) = v;
    }

    // ---- history rows (j = l0-3..l0-1) direct coalesced global reads
    const int d = threadIdx.x;
    float h0 = 0.0f, h1 = 0.0f, h2 = 0.0f;
    {
        int j = l0 - 3;
        if (j >= 0) h0 = xzb[(size_t)perm_idx(dir, j) * 512 + d];
        j = l0 - 2;
        if (j >= 0) h1 = xzb[(size_t)perm_idx(dir, j) * 512 + d];
        j = l0 - 1;
        if (j >= 0) h2 = xzb[(size_t)perm_idx(dir, j) * 512 + d];
    }
    __syncthreads();

    // ---- conv + silu, sliding 4-tap window (thread = d row)
    const float w0 = cw[d * 4 + 0], w1 = cw[d * 4 + 1], w2 = cw[d * 4 + 2], w3 = cw[d * 4 + 3];
    const float bb = cb[d];
    float r[32];
    #pragma unroll
    for (int li = 0; li < 32; ++li) {
        float cur = xt[li * 256 + d];
        r[li] = siluf_(bb + w0 * h0 + w1 * h1 + w2 * h2 + w3 * cur);
        h0 = h1; h1 = h2; h2 = cur;
    }
    {
        float* urow = ub + (size_t)d * 4096 + l0;
        #pragma unroll
        for (int q = 0; q < 8; ++q) {
            float4 v; v.x = r[q*4]; v.y = r[q*4+1]; v.z = r[q*4+2]; v.w = r[q*4+3];
            *(float4*)(urow + q * 4) = v;
        }
    }
    __syncthreads();   // all xt conv reads done before ut overwrite

    #pragma unroll
    for (int li = 0; li < 32; ++li)
        ut[li * 256 + 4 * (((d >> 2) ^ (li & 7))) + (d & 3)] = r[li];

    // ---- 40x256 GEMM: xd[40][32] = xw @ u-tile, xw staged in 32-col tiles
    {
        const int rg = threadIdx.x >> 5;
        const int li = threadIdx.x & 31;
        float acc[5];
        #pragma unroll
        for (int j = 0; j < 5; ++j) acc[j] = 0.0f;
        const int sw = (li & 7);
        for (int ct = 0; ct < 8; ++ct) {
            __syncthreads();        // ut ready (ct=0) / previous tile's reads done
            for (int idx = threadIdx.x; idx < 320; idx += 256) {
                int rr = idx >> 3, q = (idx & 7) * 4;
                *(float4*)(xws + rr * 36 + q) = *(const float4*)(xw + (size_t)rr * 256 + ct * 32 + q);
            }
            __syncthreads();
            #pragma unroll
            for (int t = 0; t < 8; ++t) {
                const int qq = t ^ sw;   // physical quad within tile (XOR-swizzle inverse)
                float4 uv = *(const float4*)(ut + li * 256 + ct * 32 + 4 * qq);
                #pragma unroll
                for (int j = 0; j < 5; ++j) {
                    float4 wv = *(const float4*)(xws + (rg * 5 + j) * 36 + 4 * t);
                    acc[j] += wv.x * uv.x + wv.y * uv.y + wv.z * uv.z + wv.w * uv.w;
                }
            }
        }
        __syncthreads();            // all ut reads done before xd alias-write
        #pragma unroll
        for (int j = 0; j < 5; ++j) xd[(rg * 5 + j) * 33 + li] = acc[j];
    }
    __syncthreads();

    // ---- B/C blocked writes (wave-coalesced) + delta
    {
        const int wv = threadIdx.x >> 6;
        const int lane = threadIdx.x & 63;
        const int n = lane >> 2, lq = lane & 3;
        #pragma unroll
        for (int j = 0; j < 2; ++j) {
            int l4 = (l0 >> 2) + j * 4 + wv;
            int li = (j * 4 + wv) * 4 + lq;
            size_t base = (((size_t)b * 1024 + l4) * 16 + n) * 4 + lq;
            Bf[base] = xd[(8 + n) * 33 + li];
            Cf[base] = xd[(24 + n) * 33 + li];
        }
    }
    {
        const int li = threadIdx.x & 31;
        float xr8[8];
        #pragma unroll
        for (int rr = 0; rr < 8; ++rr) xr8[rr] = xd[rr * 33 + li];
        #pragma unroll
        for (int k = 0; k < 32; ++k) {
            int dd = ((threadIdx.x + k * 256) >> 5);
            float4 wa = *(const float4*)(dw + dd * 8);
            float4 wb = *(const float4*)(dw + dd * 8 + 4);
            float acc = db[dd]
                + wa.x * xr8[0] + wa.y * xr8[1] + wa.z * xr8[2] + wa.w * xr8[3]
                + wb.x * xr8[4] + wb.y * xr8[5] + wb.z * xr8[6] + wb.w * xr8[7];
            deltab[(size_t)dd * 4096 + l0 + li] = softplus_fast(acc);
        }
    }
}

// ---------------------------------------------------------------------------
// K3: chunked selective scan. Block = 2 d-rows of one (b,dir): 1024 thr =
// 32 chunks x 2 d x 16 states, lane = c*32 + d2*16 + n. B/C addresses are
// d-independent -> TA coalesces duplicate halves, halving B/C L2 traffic.
// Slice pads (+8 dwords) put d2=1 8 banks away from d2=0: the wave's four
// b128 addresses occupy bank-quads {0,4,8,12} -> conflict-free.
__global__ __launch_bounds__(1024, 8) void scan_kernel(float* __restrict__ ws,
                            const float* __restrict__ Al0, const float* __restrict__ Dp0,
                            const float* __restrict__ Al1, const float* __restrict__ Dp1,
                            const float* __restrict__ Al2, const float* __restrict__ Dp2) {
    const int d0 = blockIdx.x * 2, b = blockIdx.y, dir = blockIdx.z;
    const float* Al = (dir == 0) ? Al0 : (dir == 1) ? Al1 : Al2;
    const float* Dp = (dir == 0) ? Dp0 : (dir == 1) ? Dp1 : Dp2;
    const int n  = threadIdx.x & 15;        // state 0..15
    const int d2 = (threadIdx.x >> 4) & 1;  // which d row
    const int c  = threadIdx.x >> 5;        // chunk 0..31
    const int nl = n & 7;
    const int d = d0 + d2;
    const float Ane = -1.44269504f * __expf(Al[d * 16 + n]);
    const v2f AneD = {Ane, Ane};
    const float Dd = Dp[d];
    const float* ubase = ws + U_OFF + (size_t)dir * DIR_SZ + ((size_t)(b * 256 + d0)) * 4096;
    float* dbase = ws + DELTA_OFF + (size_t)dir * DIR_SZ + ((size_t)(b * 256 + d0)) * 4096;
    float* drow = dbase + (size_t)d2 * 4096;

    __shared__ float sdu[2][32 * 260 + 8];   // +8: d2 slices 8 banks apart
    __shared__ float ps[2][1032];            // +8: same

    // stage both d rows: (delta quad | u quad) interleaved per 4 l
    for (int i = threadIdx.x; i < 2048; i += 1024) {
        int dsl = i >> 10, ii = i & 1023;
        float4 dv = ((const float4*)(dbase + (size_t)dsl * 4096))[ii];
        float4 uv = ((const float4*)(ubase + (size_t)dsl * 4096))[ii];
        int l = ii * 4;
        float* p = sdu[dsl] + (l >> 7) * 260 + (l & 127) * 2;
        *(float4*)(p) = dv; *(float4*)(p + 4) = uv;
    }
    __syncthreads();

    const v4f* Bq = (const v4f*)(ws + BC_OFF + (size_t)dir * BC_SZ)
                       + ((size_t)b * 1024 + c * 32) * 16 + n;
    const v4f* Cq = (const v4f*)(ws + BC_OFF + (size_t)dir * BC_SZ + BC_SZ / 2)
                       + ((size_t)b * 1024 + c * 32) * 16 + n;
    const v4f* sp = (const v4f*)(sdu[d2] + c * 260);
    float* Psh = ps[d2];
    float* Ssh = ps[d2] + 512;

    // Pass 1: local scan + decay-sum (packed mul pairs, fma chain)
    float S = 0.0f;
    v2f ds2 = {0.0f, 0.0f};
    #pragma unroll 8
    for (int k4 = 0; k4 < 32; ++k4) {
        v4f dq = sp[k4 * 2], uq = sp[k4 * 2 + 1];
        v4f Bv = Bq[(size_t)k4 * 16];
        v2f du0 = dq.xy * uq.xy;
        v2f du1 = dq.zw * uq.zw;
        v2f t0 = AneD * dq.xy;
        v2f t1 = AneD * dq.zw;
        v2f p0 = du0 * Bv.xy;
        v2f p1 = du1 * Bv.zw;
        ds2 += dq.xy + dq.zw;
        S = __builtin_fmaf(S, EXP2(t0.x), p0.x);
        S = __builtin_fmaf(S, EXP2(t0.y), p0.y);
        S = __builtin_fmaf(S, EXP2(t1.x), p1.x);
        S = __builtin_fmaf(S, EXP2(t1.y), p1.y);
    }
    Ssh[c * 16 + n] = S;
    Psh[c * 16 + n] = EXP2(Ane * (ds2.x + ds2.y));
    __syncthreads();
    float h = 0.0f;
    #pragma unroll 2
    for (int k = 0; k < c; ++k) h = __builtin_fmaf(h, Psh[k * 16 + n], Ssh[k * 16 + n]);

    // Pass 2: shared DPP butterfly. After 2 private levels each lane holds its
    // quad-sum; merge 4 elements into lanes by (n&1),(n&2); share ror4/ror8.
    for (int g = 0; g < 16; ++g) {
        const int j0 = g * 8 + nl;
        float uo = sdu[d2][c * 260 + ((j0 >> 2) << 3) + 4 + (j0 & 3)];   // u for output
        v4f dq0 = sp[g * 4 + 0], uq0 = sp[g * 4 + 1];
        v4f dq1 = sp[g * 4 + 2], uq1 = sp[g * 4 + 3];
        v4f Bv0 = Bq[(size_t)(g * 2) * 16], Bv1 = Bq[(size_t)(g * 2 + 1) * 16];
        v4f Cv0 = Cq[(size_t)(g * 2) * 16], Cv1 = Cq[(size_t)(g * 2 + 1) * 16];
        v2f t0 = AneD * dq0.xy, t1 = AneD * dq0.zw;
        v2f t2 = AneD * dq1.xy, t3 = AneD * dq1.zw;
        v2f q0 = dq0.xy * uq0.xy, q1 = dq0.zw * uq0.zw;
        v2f q2 = dq1.xy * uq1.xy, q3 = dq1.zw * uq1.zw;
        v2f p0 = q0 * Bv0.xy, p1 = q1 * Bv0.zw;
        v2f p2 = q2 * Bv1.xy, p3 = q3 * Bv1.zw;
        float e0 = EXP2(t0.x), e1 = EXP2(t0.y);
        float e2 = EXP2(t1.x), e3 = EXP2(t1.y);
        float e4 = EXP2(t2.x), e5 = EXP2(t2.y);
        float e6 = EXP2(t3.x), e7 = EXP2(t3.y);
        float ya0, ya1, ya2, ya3, ya4, ya5, ya6, ya7;
        h = __builtin_fmaf(h, e0, p0.x); ya0 = h * Cv0.x;
        h = __builtin_fmaf(h, e1, p0.y); ya1 = h * Cv0.y;
        h = __builtin_fmaf(h, e2, p1.x); ya2 = h * Cv0.z;
        h = __builtin_fmaf(h, e3, p1.y); ya3 = h * Cv0.w;
        h = __builtin_fmaf(h, e4, p2.x); ya4 = h * Cv1.x;
        h = __builtin_fmaf(h, e5, p2.y); ya5 = h * Cv1.y;
        h = __builtin_fmaf(h, e6, p3.x); ya6 = h * Cv1.z;
        h = __builtin_fmaf(h, e7, p3.y); ya7 = h * Cv1.w;
        // level 1: pair sums (private)
        ya0 += DPP_MOV(ya0, 0xB1); ya1 += DPP_MOV(ya1, 0xB1);
        ya2 += DPP_MOV(ya2, 0xB1); ya3 += DPP_MOV(ya3, 0xB1);
        ya4 += DPP_MOV(ya4, 0xB1); ya5 += DPP_MOV(ya5, 0xB1);
        ya6 += DPP_MOV(ya6, 0xB1); ya7 += DPP_MOV(ya7, 0xB1);
        // merge pairs of elements by n&1
        float z0 = (n & 1) ? ya1 : ya0;
        float z1 = (n & 1) ? ya3 : ya2;
        float z2 = (n & 1) ? ya5 : ya4;
        float z3 = (n & 1) ? ya7 : ya6;
        // level 2: quad sums (2 elements per reg)
        z0 += DPP_MOV(z0, 0x4E); z1 += DPP_MOV(z1, 0x4E);
        z2 += DPP_MOV(z2, 0x4E); z3 += DPP_MOV(z3, 0x4E);
        // merge by n&2 -> 4 elements per reg (element index = n&3)
        float w0 = (n & 2) ? z1 : z0;
        float w1 = (n & 2) ? z3 : z2;
        // shared levels 3,4 (ror preserves n&3)
        w0 += DPP_MOV(w0, 0x124); w1 += DPP_MOV(w1, 0x124);
        w0 += DPP_MOV(w0, 0x128); w1 += DPP_MOV(w1, 0x128);
        float ysel = (n & 4) ? w1 : w0;
        if (n < 8) drow[perm_idx(dir, c * 128 + j0)] = ysel + Dd * uo;
    }
}

// ---------------------------------------------------------------------------
// K3b: wT_out[d][o] = out_proj_w[o][d]  (runs AFTER scan; lives in dead U region)
__global__ __launch_bounds__(256) void transpose_w_kernel(const float* __restrict__ ow,
                                                          float* __restrict__ wT) {
    int idx = blockIdx.x * 256 + threadIdx.x;   // 32768
    int o = idx >> 8, d = idx & 255;            // read side coalesced (d consecutive)
    wT[(size_t)d * 128 + o] = ow[(size_t)o * 256 + d];
}

// ---------------------------------------------------------------------------
// K4: y_total = silu(z)*(yf+yb+ys); out = wT^T @ y_total.
// wT LDS-staged in 64-row tiles.
__global__ __launch_bounds__(256) void epilogue_kernel(const float* __restrict__ ws,
                                const float* __restrict__ wT,
                                float* __restrict__ out) {
    const int l0 = blockIdx.x * 16, b = blockIdx.y;
    __shared__ float yt[256 * 20];
    __shared__ float wts[64 * 128];
    const float* yf = ws + DELTA_OFF;
    const float* yb = ws + DELTA_OFF + DIR_SZ;
    const float* ysd = ws + DELTA_OFF + 2 * DIR_SZ;
    const float* xzb = ws + XZ_OFF + (size_t)b * 4096 * 512;

    // phase 1: y-sum, vectorized f4 (coalesced)
    for (int idx = threadIdx.x; idx < 256 * 4; idx += 256) {
        int d = idx >> 2, q = (idx & 3) * 4;
        size_t ro = ((size_t)(b * 256 + d)) * 4096 + l0 + q;
        float4 vf = *(const float4*)(yf + ro);
        float4 vb = *(const float4*)(yb + ro);
        float4 vs = *(const float4*)(ysd + ro);
        float4 s; s.x = vf.x + vb.x + vs.x; s.y = vf.y + vb.y + vs.y;
        s.z = vf.z + vb.z + vs.z; s.w = vf.w + vb.w + vs.w;
        *(float4*)(yt + d * 20 + q) = s;
    }
    __syncthreads();
    // phase 2: multiply silu(z), z read coalesced from xz[b][l][256+d]
    {
        const int d = threadIdx.x;
        #pragma unroll 4
        for (int li = 0; li < 16; ++li) {
            float z = xzb[(size_t)(l0 + li) * 512 + 256 + d];
            yt[d * 20 + li] *= siluf_(z);
        }
    }

    // GEMM: thread = (4 o, 2 l); wT tiled through LDS
    const int o0 = (threadIdx.x & 31) * 4;
    const int lp = (threadIdx.x >> 5) * 2;
    float a0[4], a1[4];
    #pragma unroll
    for (int j = 0; j < 4; ++j) { a0[j] = 0.0f; a1[j] = 0.0f; }
    for (int dt = 0; dt < 4; ++dt) {
        __syncthreads();        // yt ready (dt=0) / previous tile reads done
        for (int idx = threadIdx.x; idx < 64 * 32; idx += 256) {
            int dd = idx >> 5, q = (idx & 31) * 4;
            *(float4*)(wts + dd * 128 + q) = *(const float4*)(wT + (size_t)(dt * 64 + dd) * 128 + q);
        }
        __syncthreads();
        #pragma unroll 4
        for (int dl = 0; dl < 64; ++dl) {
            float4 w = *(const float4*)(wts + dl * 128 + o0);
            float2 y = *(const float2*)(yt + (dt * 64 + dl) * 20 + lp);
            a0[0] += w.x * y.x; a0[1] += w.y * y.x; a0[2] += w.z * y.x; a0[3] += w.w * y.x;
            a1[0] += w.x * y.y; a1[1] += w.y * y.y; a1[2] += w.z * y.y; a1[3] += w.w * y.y;
        }
    }
    float4 s0; s0.x = a0[0]; s0.y = a0[1]; s0.z = a0[2]; s0.w = a0[3];
    float4 s1; s1.x = a1[0]; s1.y = a1[1]; s1.z = a1[2]; s1.w = a1[3];
    *(float4*)(out + ((size_t)(b * 4096 + l0 + lp)) * 128 + o0) = s0;
    *(float4*)(out + ((size_t)(b * 4096 + l0 + lp + 1)) * 128 + o0) = s1;
}

// ---------------------------------------------------------------------------
extern "C" void kernel_launch(void* const* d_in, const int* in_sizes, int n_in,
                              void* d_out, int out_size, void* d_ws, size_t ws_size,
                              hipStream_t stream) {
    const float* x_in = (const float*)d_in[0];
    const float* ipw  = (const float*)d_in[1];
    const float* cw[3]  = {(const float*)d_in[2],  (const float*)d_in[9],  (const float*)d_in[16]};
    const float* cb[3]  = {(const float*)d_in[3],  (const float*)d_in[10], (const float*)d_in[17]};
    const float* xpw[3] = {(const float*)d_in[4],  (const float*)d_in[11], (const float*)d_in[18]};
    const float* dtw[3] = {(const float*)d_in[5],  (const float*)d_in[12], (const float*)d_in[19]};
    const float* dtb[3] = {(const float*)d_in[6],  (const float*)d_in[13], (const float*)d_in[20]};
    const float* alog[3]= {(const float*)d_in[7],  (const float*)d_in[14], (const float*)d_in[21]};
    const float* dp[3]  = {(const float*)d_in[8],  (const float*)d_in[15], (const float*)d_in[22]};
    const float* ow   = (const float*)d_in[23];
    float* ws  = (float*)d_ws;
    float* out = (float*)d_out;

    transpose_in_kernel<<<dim3(256), 256, 0, stream>>>(ipw, ws + WTIN_OFF);
    inproj_kernel<<<dim3(256, 4), 256, 0, stream>>>(x_in, ws + WTIN_OFF, ws);
    front_kernel<<<dim3(128, 4, 3), 256, 0, stream>>>(ws,
        xpw[0], xpw[1], xpw[2], dtw[0], dtw[1], dtw[2], dtb[0], dtb[1], dtb[2],
        cw[0], cb[0], cw[1], cb[1], cw[2], cb[2]);
    scan_kernel<<<dim3(128, 4, 3), 1024, 0, stream>>>(ws,
        alog[0], dp[0], alog[1], dp[1], alog[2], dp[2]);
    transpose_w_kernel<<<dim3(128), 256, 0, stream>>>(ow, ws + WTOUT_OFF);
    epilogue_kernel<<<dim3(256, 4), 256, 0, stream>>>(ws, ws + WTOUT_OFF, out);
}